// Round 1
// 848.061 us; speedup vs baseline: 1.3498x; 1.3498x over previous
//
#include <hip/hip_runtime.h>
#include <hip/hip_bf16.h>
#include <stdint.h>
#include <math.h>

// MoE: x[4,2048,1024] fp32, Wg[1024,8], bg[8], W1[8,1024,4096], b1[8,4096],
//      W2[8,4096,1024], b2[8,1024].  top-2 of softmax over 8 experts, no renorm.
// fp32 gating -> deterministic counting-sort routing (no global atomic storms)
// -> routed bf16 MFMA grouped GEMMs: 128x128 block tile, FOUR waves of 64x64
// (acc[4][4] = 64 AGPRs/wave -> ~228 unified regs -> 2 waves/SIMD, vs the old
// 2-wave 64x128 acc[4][8] = 276 regs -> 1 wave/SIMD, which capped occupancy at
// 12.5% and left MfmaUtil at 11%).  BK=64, global_load_lds w=16, XOR-swizzled
// LDS (slot s of row r holds global chunk s^(r&7)).  This is the m97-verified
// 128^2 structure (874-912 TF on square bf16 GEMM).

#define TOKENS   8192
#define DIM      1024
#define HIDN     4096
#define NEXP     8
#define PAIRS    (TOKENS * 2)                 // 16384
#define MAXROWS  (PAIRS + NEXP * 64)          // 16896 (<=127 pad per expert, 8 experts)
#define MAXTILES 136
#define NHB      128                          // histogram blocks (128 pairs each)

typedef __attribute__((ext_vector_type(8))) short short8;   // 8 x bf16 = 4 VGPRs
typedef __attribute__((ext_vector_type(4))) float f32x4;

#define AS1 __attribute__((address_space(1)))
#define AS3 __attribute__((address_space(3)))

__device__ inline short bf16b(float f) {
    __hip_bfloat16 h = __float2bfloat16(f);
    return *reinterpret_cast<short*>(&h);
}

// ---------------------------------------------------------------- gating ----
// one wave per token: 8 fp32 logits, softmax, top-2 (strict > keeps lowest
// index on ties, matching jax.lax.top_k). No global atomics.
__global__ __launch_bounds__(256) void gating_kernel(
    const float* __restrict__ x, const float* __restrict__ Wg,
    const float* __restrict__ bg,
    int* __restrict__ topk_e, float* __restrict__ topk_w)
{
    int t    = blockIdx.x * 4 + (threadIdx.x >> 6);
    int lane = threadIdx.x & 63;
    if (t >= TOKENS) return;
    const float* xr = x + (size_t)t * DIM;

    float acc[8];
#pragma unroll
    for (int e = 0; e < 8; ++e) acc[e] = 0.f;

#pragma unroll 4
    for (int j = 0; j < DIM / 64; ++j) {
        int idx = j * 64 + lane;
        float xv = xr[idx];
        const float* wr = Wg + (size_t)idx * 8;
        float4 w0 = *(const float4*)(wr);
        float4 w1 = *(const float4*)(wr + 4);
        acc[0] += xv * w0.x; acc[1] += xv * w0.y;
        acc[2] += xv * w0.z; acc[3] += xv * w0.w;
        acc[4] += xv * w1.x; acc[5] += xv * w1.y;
        acc[6] += xv * w1.z; acc[7] += xv * w1.w;
    }
#pragma unroll
    for (int off = 32; off > 0; off >>= 1)
#pragma unroll
        for (int e = 0; e < 8; ++e) acc[e] += __shfl_down(acc[e], off);

    if (lane == 0) {
        float lg[8];
#pragma unroll
        for (int e = 0; e < 8; ++e) lg[e] = acc[e] + bg[e];
        float mx = lg[0];
#pragma unroll
        for (int e = 1; e < 8; ++e) mx = fmaxf(mx, lg[e]);
        float p[8]; float s = 0.f;
#pragma unroll
        for (int e = 0; e < 8; ++e) { p[e] = expf(lg[e] - mx); s += p[e]; }
        int e0 = 0;
#pragma unroll
        for (int e = 1; e < 8; ++e) if (p[e] > p[e0]) e0 = e;
        int e1 = -1;
#pragma unroll
        for (int e = 0; e < 8; ++e)
            if (e != e0 && (e1 < 0 || p[e] > p[e1])) e1 = e;
        float inv = 1.f / s;
        topk_e[t * 2 + 0] = e0;  topk_w[t * 2 + 0] = p[e0] * inv;
        topk_e[t * 2 + 1] = e1;  topk_w[t * 2 + 1] = p[e1] * inv;
    }
}

// ------------------------------------------------------------------ hist ----
// per-128-pair-block expert histogram (LDS atomics only).
__global__ __launch_bounds__(128) void hist_kernel(
    const int* __restrict__ topk_e, int* __restrict__ hist)
{
    __shared__ int h[8];
    int t = threadIdx.x, b = blockIdx.x;
    if (t < 8) h[t] = 0;
    __syncthreads();
    atomicAdd(&h[topk_e[b * 128 + t]], 1);
    __syncthreads();
    if (t < 8) hist[b * 8 + t] = h[t];
}

// ------------------------------------------------------------------ plan ----
// exclusive scan of hist over blocks per expert -> per-block bases; 128-aligned
// expert segments; flat M-tile list.  1 block x 128 threads.
__global__ __launch_bounds__(128) void plan_kernel(
    const int* __restrict__ hist, int* __restrict__ base,
    int* __restrict__ tile_e, int* __restrict__ tile_row0, int* __restrict__ n_tiles)
{
    __shared__ int sx[8][NHB];
    __shared__ int tot[8];
    __shared__ int segs[8];
    __shared__ int wtot[2];
    int t = threadIdx.x, lane = t & 63, wid = t >> 6;
#pragma unroll
    for (int e = 0; e < 8; ++e) {
        int hv = hist[t * 8 + e];
        int v = hv;
#pragma unroll
        for (int off = 1; off < 64; off <<= 1) {
            int n = __shfl_up(v, off);
            if (lane >= off) v += n;
        }
        if (lane == 63) wtot[wid] = v;
        __syncthreads();
        int incl = v + (wid ? wtot[0] : 0);
        sx[e][t] = incl - hv;
        if (t == NHB - 1) tot[e] = incl;
        __syncthreads();
    }
    if (t == 0) {
        int off = 0, nt = 0;
        for (int e = 0; e < 8; ++e) {
            segs[e] = off;
            int tl = (tot[e] + 127) >> 7;
            for (int i = 0; i < tl; ++i) { tile_e[nt] = e; tile_row0[nt] = off + i * 128; ++nt; }
            off += tl * 128;
        }
        *n_tiles = nt;
    }
    __syncthreads();
#pragma unroll
    for (int e = 0; e < 8; ++e) base[t * 8 + e] = segs[e] + sx[e][t];
}

// ----------------------------------------------------------- gather rank ----
// deterministic row slot per pair (LDS-atomic local rank + scanned base).
__global__ __launch_bounds__(128) void gather_rank(
    const int* __restrict__ topk_e, const float* __restrict__ topk_w,
    const int* __restrict__ base, int* __restrict__ pair_row,
    int* __restrict__ row_token, float* __restrict__ row_gate)
{
    __shared__ int cnt[8];
    int t = threadIdx.x, b = blockIdx.x;
    if (t < 8) cnt[t] = 0;
    __syncthreads();
    int pr = b * 128 + t;
    int e  = topk_e[pr];
    int lr = atomicAdd(&cnt[e], 1);
    int row = base[b * 8 + e] + lr;
    pair_row[pr]   = row;
    row_token[row] = pr >> 1;
    row_gate[row]  = topk_w[pr];
}

// ---------------------------------------------------------- scatter copy ----
// copy x rows -> contiguous bf16 expert segments.  256 blocks x 64 pairs.
__global__ __launch_bounds__(256) void scatter_copy(
    const float* __restrict__ x, const int* __restrict__ pair_row,
    __hip_bfloat16* __restrict__ xe)
{
    int b = blockIdx.x;
    int wv = threadIdx.x >> 6, lane = threadIdx.x & 63;
#pragma unroll 4
    for (int i = 0; i < 16; ++i) {
        int p   = b * 64 + i * 4 + wv;
        int row = pair_row[p];
        int tok = p >> 1;
        const float* xr = x + (size_t)tok * DIM;
        __hip_bfloat16* xo = xe + (size_t)row * DIM;
        int idx = lane * 16;
        float4 v0 = *(const float4*)(xr + idx);
        float4 v1 = *(const float4*)(xr + idx + 4);
        float4 v2 = *(const float4*)(xr + idx + 8);
        float4 v3 = *(const float4*)(xr + idx + 12);
        short8 o0, o1;
        o0[0] = bf16b(v0.x); o0[1] = bf16b(v0.y); o0[2] = bf16b(v0.z); o0[3] = bf16b(v0.w);
        o0[4] = bf16b(v1.x); o0[5] = bf16b(v1.y); o0[6] = bf16b(v1.z); o0[7] = bf16b(v1.w);
        o1[0] = bf16b(v2.x); o1[1] = bf16b(v2.y); o1[2] = bf16b(v2.z); o1[3] = bf16b(v2.w);
        o1[4] = bf16b(v3.x); o1[5] = bf16b(v3.y); o1[6] = bf16b(v3.z); o1[7] = bf16b(v3.w);
        *(short8*)(xo + idx)     = o0;
        *(short8*)(xo + idx + 8) = o1;
    }
}

// --------------------------------------------------- weight transpose+cvt ----
// src: [E][rows][cols] fp32 -> dst: [E][cols][rows] bf16.  All 256 threads in
// the write phase, 8B stores, <=2-way LDS conflicts.
__global__ __launch_bounds__(256) void transpose_cvt_kernel(
    const float* __restrict__ src, __hip_bfloat16* __restrict__ dst,
    int rows, int cols)
{
    __shared__ float tile[32][33];
    int e  = blockIdx.z;
    const float* s = src + (size_t)e * rows * cols;
    __hip_bfloat16* d = dst + (size_t)e * rows * cols;
    int c0 = blockIdx.x * 32, r0 = blockIdx.y * 32;
    int tx = threadIdx.x & 31, ty = threadIdx.x >> 5;   // 32 x 8
#pragma unroll
    for (int j = 0; j < 4; ++j) {
        int rr = ty + j * 8;
        tile[rr][tx] = s[(size_t)(r0 + rr) * cols + c0 + tx];
    }
    __syncthreads();
    int t  = threadIdx.x;
    int cr = t >> 3;        // dst row within tile (0..31)
    int g  = t & 7;         // 4-elem group (0..7)
    ushort o[4];
#pragma unroll
    for (int j = 0; j < 4; ++j) o[j] = (ushort)bf16b(tile[g * 4 + j][cr]);
    *(uint2*)(d + (size_t)(c0 + cr) * rows + r0 + g * 4) = *(uint2*)o;
}

// ------------------------------------------------------------------ GEMM ----
// C[M,N] = A[M,K] * B[N,K]^T per expert tile.  128x128 block tile, BK=64,
// FOUR waves in a 2x2 grid, each computing a 64x64 quadrant (4x4 grid of
// 16x16x32 MFMA -> acc[4][4] = 64 AGPRs/wave; ~228 unified regs -> 2
// waves/SIMD; the old 2-wave 64x128 layout needed 276 regs -> 1 wave/SIMD).
// global_load_lds w=16 with XOR swizzle (slot s of row r holds global chunk
// s^(r&7); read slot (kk*4+quad)^(r&7) inverts it since read row&7 == r&7).
// MODE 1: hid = bf16(relu(acc + b1))          (N = 4096)
// MODE 2: atomicAdd(out[token], gate*(acc+b2)) (N = 1024)
template <int MODE>
__global__ __launch_bounds__(256) void moe_gemm(
    const __hip_bfloat16* __restrict__ A,
    const __hip_bfloat16* __restrict__ Bw,       // [E][N][K]
    const float* __restrict__ bias,              // [E][N]
    const int* __restrict__ tile_e, const int* __restrict__ tile_row0,
    const int* __restrict__ n_tiles,
    int K, int N,
    __hip_bfloat16* __restrict__ hid,
    const int* __restrict__ row_token, const float* __restrict__ row_gate,
    float* __restrict__ out)
{
    int tidx = blockIdx.x;
    if (tidx >= *n_tiles) return;
    int e  = tile_e[tidx];
    int m0 = tile_row0[tidx];
    int n0 = blockIdx.y * 128;
    const __hip_bfloat16* Bb = Bw + (size_t)e * N * K;

    __shared__ __hip_bfloat16 lA[128 * 64];   // 16 KB
    __shared__ __hip_bfloat16 lB[128 * 64];   // 16 KB

    int tid  = threadIdx.x;
    int w    = tid >> 6;          // wave 0..3
    int l    = tid & 63;
    int r    = l & 15;
    int quad = l >> 4;
    int subrow = l >> 3;                      // staging row-in-chunk 0..7
    int cswz   = ((l & 7) ^ subrow) * 16;     // swizzled byte col 0..112
    int wm = (w >> 1) * 64;                   // wave row offset in tile
    int wn = (w & 1) * 64;                    // wave col offset in tile

    const f32x4 fzero = {0.f, 0.f, 0.f, 0.f};
    f32x4 acc[4][4];
#pragma unroll
    for (int mi = 0; mi < 4; ++mi)
#pragma unroll
        for (int ni = 0; ni < 4; ++ni) acc[mi][ni] = fzero;

    const size_t ldb = (size_t)K * 2;
    int rsw = (r & 7);

    for (int k0 = 0; k0 < K; k0 += 64) {
#pragma unroll
        for (int i = 0; i < 4; ++i) {
            int chunk = i * 4 + w;               // 0..15, wave-uniform
            int rowA  = chunk * 8 + subrow;      // 0..127
            const char* gA = (const char*)A + (size_t)(m0 + rowA) * ldb + (size_t)k0 * 2 + cswz;
            const char* gB = (const char*)Bb + (size_t)(n0 + rowA) * ldb + (size_t)k0 * 2 + cswz;
            char* sA = (char*)lA + chunk * 1024;   // + lane*16 implicit
            char* sB = (char*)lB + chunk * 1024;
            __builtin_amdgcn_global_load_lds((const AS1 void*)gA, (AS3 void*)sA, 16, 0, 0);
            __builtin_amdgcn_global_load_lds((const AS1 void*)gB, (AS3 void*)sB, 16, 0, 0);
        }
        __syncthreads();
#pragma unroll
        for (int kk = 0; kk < 2; ++kk) {
            int slot = ((kk * 4 + quad) ^ rsw) * 16;
            short8 aF[4], bF[4];
#pragma unroll
            for (int mi = 0; mi < 4; ++mi) {
                int row = wm + mi * 16 + r;
                aF[mi] = *(const short8*)((const char*)lA + row * 128 + slot);
            }
#pragma unroll
            for (int ni = 0; ni < 4; ++ni) {
                int row = wn + ni * 16 + r;
                bF[ni] = *(const short8*)((const char*)lB + row * 128 + slot);
            }
#pragma unroll
            for (int mi = 0; mi < 4; ++mi)
#pragma unroll
                for (int ni = 0; ni < 4; ++ni)
                    acc[mi][ni] = __builtin_amdgcn_mfma_f32_16x16x32_bf16(
                        aF[mi], bF[ni], acc[mi][ni], 0, 0, 0);
        }
        __syncthreads();
    }

    if (MODE == 1) {
#pragma unroll
        for (int mi = 0; mi < 4; ++mi)
#pragma unroll
            for (int i = 0; i < 4; ++i) {
                int row = m0 + wm + mi * 16 + quad * 4 + i;
                size_t rb = (size_t)row * N;
#pragma unroll
                for (int ni = 0; ni < 4; ++ni) {
                    int col = n0 + wn + ni * 16 + r;
                    float v = acc[mi][ni][i] + bias[e * N + col];
                    hid[rb + col] = __float2bfloat16(fmaxf(v, 0.f));
                }
            }
    } else {
#pragma unroll
        for (int mi = 0; mi < 4; ++mi)
#pragma unroll
            for (int i = 0; i < 4; ++i) {
                int row = m0 + wm + mi * 16 + quad * 4 + i;
                int token = row_token[row];
                if ((unsigned)token < (unsigned)TOKENS) {
                    float g = row_gate[row];
                    float* orow = out + (size_t)token * DIM;
#pragma unroll
                    for (int ni = 0; ni < 4; ++ni) {
                        int col = n0 + wn + ni * 16 + r;
                        float v = acc[mi][ni][i] + bias[e * N + col];
                        atomicAdd(orow + col, g * v);
                    }
                }
            }
    }
}

// ---------------------------------------------------------------- launch ----
extern "C" void kernel_launch(void* const* d_in, const int* in_sizes, int n_in,
                              void* d_out, int out_size, void* d_ws, size_t ws_size,
                              hipStream_t stream) {
    const float* x  = (const float*)d_in[0];
    const float* Wg = (const float*)d_in[1];
    const float* bg = (const float*)d_in[2];
    const float* W1 = (const float*)d_in[3];
    const float* b1 = (const float*)d_in[4];
    const float* W2 = (const float*)d_in[5];
    const float* b2 = (const float*)d_in[6];
    float* out = (float*)d_out;

    // workspace layout (~313 MB)
    char* w = (char*)d_ws;
    int*   n_tiles   = (int*)(w + 0);
    int*   tile_e    = (int*)(w + 256);
    int*   tile_row0 = (int*)(w + 2048);
    int*   hist      = (int*)(w + 4096);                       // 4 KB
    int*   base      = (int*)(w + 8192);                       // 4 KB
    int*   topk_e    = (int*)(w + 12288);                      // 64 KB
    float* topk_w    = (float*)(w + 77824);                    // 64 KB
    int*   pair_row  = (int*)(w + 143360);                     // 64 KB
    int*   row_token = (int*)(w + 208896);                     // 68 KB
    float* row_gate  = (float*)(w + 278528);                   // 68 KB
    __hip_bfloat16* xe  = (__hip_bfloat16*)(w + 348160);       // 34.0 MB
    __hip_bfloat16* hid = (__hip_bfloat16*)(w + 35999744ULL);  // 136.0 MB
    __hip_bfloat16* W1b = (__hip_bfloat16*)(w + 178606080ULL); // 67.1 MB
    __hip_bfloat16* W2b = (__hip_bfloat16*)(w + 245714944ULL); // 67.1 MB
    // total: 312,823,808 bytes

    hipMemsetAsync(out, 0, (size_t)out_size * sizeof(float), stream); // out = 0

    gating_kernel<<<TOKENS / 4, 256, 0, stream>>>(x, Wg, bg, topk_e, topk_w);
    hist_kernel<<<NHB, 128, 0, stream>>>(topk_e, hist);
    plan_kernel<<<1, 128, 0, stream>>>(hist, base, tile_e, tile_row0, n_tiles);
    gather_rank<<<NHB, 128, 0, stream>>>(topk_e, topk_w, base, pair_row,
                                         row_token, row_gate);
    scatter_copy<<<256, 256, 0, stream>>>(x, pair_row, xe);

    // W1: [E][1024][4096] -> W1b [E][4096][1024]
    transpose_cvt_kernel<<<dim3(HIDN / 32, DIM / 32, NEXP), 256, 0, stream>>>(W1, W1b, DIM, HIDN);
    // W2: [E][4096][1024] -> W2b [E][1024][4096]
    transpose_cvt_kernel<<<dim3(DIM / 32, HIDN / 32, NEXP), 256, 0, stream>>>(W2, W2b, HIDN, DIM);

    // GEMM1: hid = relu(xe @ W1 + b1)     M=rows, K=1024, N=4096
    moe_gemm<1><<<dim3(MAXTILES, HIDN / 128), 256, 0, stream>>>(
        xe, W1b, b1, tile_e, tile_row0, n_tiles, DIM, HIDN,
        hid, nullptr, nullptr, nullptr);
    // GEMM2: out += gate * (hid @ W2 + b2) M=rows, K=4096, N=1024
    moe_gemm<2><<<dim3(MAXTILES, DIM / 128), 256, 0, stream>>>(
        hid, W2b, b2, tile_e, tile_row0, n_tiles, HIDN, DIM,
        nullptr, row_token, row_gate, out);
}